// Round 7
// baseline (184.080 us; speedup 1.0000x reference)
//
#include <hip/hip_runtime.h>

#define NN   4096
#define FIN  512
#define FOUT 256
#define ALPHA 0.2f

typedef __attribute__((ext_vector_type(8))) short short8;
typedef __attribute__((ext_vector_type(4))) float f32x4;
typedef unsigned short u16;

__device__ __forceinline__ u16 f2bf(float x) {   // round-to-nearest-even
    union { float f; unsigned u; } v; v.f = x;
    unsigned r = v.u + 0x7FFF + ((v.u >> 16) & 1);
    return (u16)(r >> 16);
}

// ---------------- Kernel 0: Wt[f][k] bf16 = transpose(W [k][f] fp32) ----------------
__global__ __launch_bounds__(256) void k_wt(const float* __restrict__ W,
                                            u16* __restrict__ Wt) {
    __shared__ float s[64 * 65];
    const int t  = threadIdx.x;
    const int f0 = blockIdx.x * 64;
    const int k0 = blockIdx.y * 64;
    #pragma unroll
    for (int p = 0; p < 4; ++p) {
        int q = t + 256 * p, rr = q >> 4, cc = q & 15;
        float4 w4 = *(const float4*)&W[(size_t)(k0 + rr) * FOUT + f0 + cc * 4];
        s[(cc * 4 + 0) * 65 + rr] = w4.x;
        s[(cc * 4 + 1) * 65 + rr] = w4.y;
        s[(cc * 4 + 2) * 65 + rr] = w4.z;
        s[(cc * 4 + 3) * 65 + rr] = w4.w;
    }
    __syncthreads();
    #pragma unroll
    for (int p = 0; p < 4; ++p) {
        int q = t + 256 * p, f = q >> 4, kg = q & 15;
        ushort4 o;
        o.x = f2bf(s[f * 65 + kg * 4 + 0]);
        o.y = f2bf(s[f * 65 + kg * 4 + 1]);
        o.z = f2bf(s[f * 65 + kg * 4 + 2]);
        o.w = f2bf(s[f * 65 + kg * 4 + 3]);
        *(ushort4*)&Wt[(size_t)(f0 + f) * FIN + k0 + kg * 4] = o;
    }
}

// ------- Kernel 1: whT bf16 tiles + partial f_src/f_dst (k_vec folded in) -------
#define HS 520   // u16 LDS row stride
__global__ __launch_bounds__(256) void k_proj(const float* __restrict__ h,
                                              const u16* __restrict__ Wt,
                                              const float* __restrict__ bias,
                                              const float* __restrict__ a1,
                                              const float* __restrict__ a2,
                                              u16* __restrict__ whT,
                                              float* __restrict__ psrc,
                                              float* __restrict__ pdst) {
    __shared__ u16   s_h[32 * HS];     // 32 x 512 bf16
    __shared__ float s_red[4 * 32];
    const int t  = threadIdx.x;
    const int f0 = blockIdx.x * 64;
    const int i0 = blockIdx.y * 32;
    #pragma unroll
    for (int p = 0; p < 16; ++p) {
        int q = t + 256 * p, row = q >> 7, c4 = q & 127;
        float4 v = *(const float4*)&h[(size_t)(i0 + row) * FIN + c4 * 4];
        ushort4 o; o.x = f2bf(v.x); o.y = f2bf(v.y); o.z = f2bf(v.z); o.w = f2bf(v.w);
        *(ushort4*)&s_h[row * HS + c4 * 4] = o;
    }
    __syncthreads();
    const int w = t >> 6, l = t & 63, n = l & 15, quad = l >> 4;
    const int hh = w & 1, fh = w >> 1;
    f32x4 acc[2] = {{0.f,0.f,0.f,0.f},{0.f,0.f,0.f,0.f}};
    #pragma unroll
    for (int k0 = 0; k0 < FIN; k0 += 32) {
        short8 a  = *(const short8*)&s_h[(hh * 16 + n) * HS + k0 + quad * 8];
        short8 b0 = *(const short8*)&Wt[(size_t)(f0 + fh * 32 + n) * FIN + k0 + quad * 8];
        short8 b1 = *(const short8*)&Wt[(size_t)(f0 + fh * 32 + 16 + n) * FIN + k0 + quad * 8];
        acc[0] = __builtin_amdgcn_mfma_f32_16x16x32_bf16(a, b0, acc[0], 0, 0, 0);
        acc[1] = __builtin_amdgcn_mfma_f32_16x16x32_bf16(a, b1, acc[1], 0, 0, 0);
    }
    u16* wt_tile = whT + (size_t)(i0 >> 5) * (FOUT * 32);
    float a1v[2], a2v[2];
    a1v[0] = a1[f0 + fh * 32 + n];      a1v[1] = a1[f0 + fh * 32 + 16 + n];
    a2v[0] = a2[f0 + fh * 32 + n];      a2v[1] = a2[f0 + fh * 32 + 16 + n];
    float ps[4] = {0.f,0.f,0.f,0.f}, pd[4] = {0.f,0.f,0.f,0.f};
    #pragma unroll
    for (int u = 0; u < 2; ++u) {
        const int f = f0 + fh * 32 + u * 16 + n;
        const float bv = bias[f];
        #pragma unroll
        for (int r = 0; r < 4; ++r) {
            float val = acc[u][r] + bv;                      // D: row=quad*4+r, col=n
            wt_tile[f * 32 + hh * 16 + quad * 4 + r] = f2bf(val);
            ps[r] += val * a1v[u];
            pd[r] += val * a2v[u];
        }
    }
    #pragma unroll
    for (int m = 1; m < 16; m <<= 1) {
        #pragma unroll
        for (int r = 0; r < 4; ++r) { ps[r] += __shfl_xor(ps[r], m); pd[r] += __shfl_xor(pd[r], m); }
    }
    if (n == 0) {
        #pragma unroll
        for (int r = 0; r < 4; ++r) {
            int il = hh * 16 + quad * 4 + r;
            s_red[fh * 32 + il]       = ps[r];
            s_red[64 + fh * 32 + il]  = pd[r];
        }
    }
    __syncthreads();
    if (t < 32) {
        psrc[(size_t)blockIdx.x * NN + i0 + t] = s_red[t]      + s_red[32 + t];
        pdst[(size_t)blockIdx.x * NN + i0 + t] = s_red[64 + t] + s_red[96 + t];
    }
}

// ------ Kernel 2: barrier-free fused mask+exp + MFMA P@wh -> partials ------
// Each lane computes its OWN A-fragment: A[m=lane&15][k=quad*8+j] needs
// p[i0+m][j0+quad*8+jj] -> lane-local from adj (two int4, 128B row runs).
// 4 waves/block share the 16-row tile (identical A redundantly, L1-served adj),
// each owns a 64-f slice of whT B-frags. NO __syncthreads in the K-loop.
#define BI 16
#define TJ 32
#define CC 4
#define JCHUNK (NN / CC)          // 1024
#define NITER  (JCHUNK / TJ)      // 32
__global__ __launch_bounds__(256) void k_attn(const int* __restrict__ adj,
                                              const u16* __restrict__ whT,
                                              const float* __restrict__ psrc,
                                              const float* __restrict__ pdst,
                                              const float* __restrict__ ab,
                                              float* __restrict__ part,
                                              float* __restrict__ psum) {
    __shared__ float s_fd[JCHUNK];     // 4 KB
    const int t  = threadIdx.x;
    const int i0 = blockIdx.x * BI;
    const int c  = blockIdx.y;
    const int jbeg = c * JCHUNK;
    const int w = t >> 6, l = t & 63, n = l & 15, quad = l >> 4;

    // ---- preamble: combine the 4 f-slab partials of fd into LDS; fs in reg ----
    {
        float4 v0 = ((const float4*)&pdst[jbeg])[t];
        float4 v1 = ((const float4*)&pdst[NN + jbeg])[t];
        float4 v2 = ((const float4*)&pdst[2 * NN + jbeg])[t];
        float4 v3 = ((const float4*)&pdst[3 * NN + jbeg])[t];
        float4 o;
        o.x = v0.x + v1.x + v2.x + v3.x; o.y = v0.y + v1.y + v2.y + v3.y;
        o.z = v0.z + v1.z + v2.z + v3.z; o.w = v0.w + v1.w + v2.w + v3.w;
        ((float4*)s_fd)[t] = o;
    }
    const float fsm = psrc[i0 + n] + psrc[NN + i0 + n] + psrc[2 * NN + i0 + n]
                    + psrc[3 * NN + i0 + n] + ab[0];
    __syncthreads();                   // the only barrier in this kernel

    const int* arow = adj + (size_t)(i0 + n) * NN + jbeg + quad * 8;
    int4 a0 = *(const int4*)arow;          // jj 0..3
    int4 a1 = *(const int4*)(arow + 4);    // jj 4..7

    f32x4 acc[4] = {{0.f,0.f,0.f,0.f},{0.f,0.f,0.f,0.f},{0.f,0.f,0.f,0.f},{0.f,0.f,0.f,0.f}};
    float rs = 0.f;

    for (int it = 0; it < NITER; ++it) {
        const int jo = it * TJ;
        float4 g0 = *(const float4*)&s_fd[jo + quad * 8];
        float4 g1 = *(const float4*)&s_fd[jo + quad * 8 + 4];
        short8 af;
        {
            float x, p;
            x = fsm + g0.x; x = x > 0.f ? x : ALPHA * x; p = a0.x > 0 ? __expf(x) : 0.f; af[0] = (short)f2bf(p); rs += p;
            x = fsm + g0.y; x = x > 0.f ? x : ALPHA * x; p = a0.y > 0 ? __expf(x) : 0.f; af[1] = (short)f2bf(p); rs += p;
            x = fsm + g0.z; x = x > 0.f ? x : ALPHA * x; p = a0.z > 0 ? __expf(x) : 0.f; af[2] = (short)f2bf(p); rs += p;
            x = fsm + g0.w; x = x > 0.f ? x : ALPHA * x; p = a0.w > 0 ? __expf(x) : 0.f; af[3] = (short)f2bf(p); rs += p;
            x = fsm + g1.x; x = x > 0.f ? x : ALPHA * x; p = a1.x > 0 ? __expf(x) : 0.f; af[4] = (short)f2bf(p); rs += p;
            x = fsm + g1.y; x = x > 0.f ? x : ALPHA * x; p = a1.y > 0 ? __expf(x) : 0.f; af[5] = (short)f2bf(p); rs += p;
            x = fsm + g1.z; x = x > 0.f ? x : ALPHA * x; p = a1.z > 0 ? __expf(x) : 0.f; af[6] = (short)f2bf(p); rs += p;
            x = fsm + g1.w; x = x > 0.f ? x : ALPHA * x; p = a1.w > 0 ? __expf(x) : 0.f; af[7] = (short)f2bf(p); rs += p;
        }
        // prefetch next iter's adj (in flight through the MFMA phase)
        if (it + 1 < NITER) {
            a0 = *(const int4*)(arow + TJ);
            a1 = *(const int4*)(arow + TJ + 4);
            arow += TJ;
        }
        // B-frags from L2-hot whT; this wave's 64-f slice
        const u16* tb = whT + (size_t)((jbeg + jo) >> 5) * (FOUT * 32) + quad * 8;
        #pragma unroll
        for (int u = 0; u < 4; ++u) {
            short8 b = *(const short8*)&tb[(w * 64 + u * 16 + n) * 32];
            acc[u] = __builtin_amdgcn_mfma_f32_16x16x32_bf16(af, b, acc[u], 0, 0, 0);
        }
    }
    // ---- row denominators: sum the 4 quads; lane m holds row i0+m ----
    rs += __shfl_xor(rs, 16);
    rs += __shfl_xor(rs, 32);
    if (t < BI) psum[(size_t)c * NN + i0 + t] = rs;   // wave 0, quad 0 lanes
    // ---- partial numerators: D row = quad*4+r, col = n ----
    float* pc = part + ((size_t)c * NN + i0) * FOUT + w * 64;
    #pragma unroll
    for (int u = 0; u < 4; ++u)
        #pragma unroll
        for (int r = 0; r < 4; ++r)
            pc[(size_t)(quad * 4 + r) * FOUT + u * 16 + n] = acc[u][r];
}

// ------ Kernel 3: combine partials, normalize, elu ------
__global__ __launch_bounds__(256) void k_fin(const float* __restrict__ part,
                                             const float* __restrict__ psum,
                                             float* __restrict__ out) {
    const int g = blockIdx.x * 256 + threadIdx.x;
    const int i = g >> 6;
    const size_t s4 = (size_t)NN * (FOUT / 4);
    float4 a = ((const float4*)part)[g];
    float s = psum[i];
    #pragma unroll
    for (int c = 1; c < CC; ++c) {
        float4 bb = ((const float4*)part)[g + (size_t)c * s4];
        a.x += bb.x; a.y += bb.y; a.z += bb.z; a.w += bb.w;
        s += psum[(size_t)c * NN + i];
    }
    const float inv = 1.0f / s;
    a.x *= inv; a.y *= inv; a.z *= inv; a.w *= inv;
    a.x = a.x > 0.f ? a.x : __expf(a.x) - 1.f;
    a.y = a.y > 0.f ? a.y : __expf(a.y) - 1.f;
    a.z = a.z > 0.f ? a.z : __expf(a.z) - 1.f;
    a.w = a.w > 0.f ? a.w : __expf(a.w) - 1.f;
    ((float4*)out)[g] = a;
}

extern "C" void kernel_launch(void* const* d_in, const int* in_sizes, int n_in,
                              void* d_out, int out_size, void* d_ws, size_t ws_size,
                              hipStream_t stream) {
    const int*   adj = (const int*)  d_in[0];
    const float* h   = (const float*)d_in[1];
    const float* W   = (const float*)d_in[2];
    const float* b   = (const float*)d_in[3];
    const float* a1  = (const float*)d_in[4];
    const float* a2  = (const float*)d_in[5];
    const float* ab  = (const float*)d_in[6];
    float* out = (float*)d_out;

    // layout: psrc[4][NN] | pdst[4][NN] | psum[CC][NN] | part[CC][NN][FOUT] |
    // Wt (u16) | whT (u16)   (~20 MB total)
    float* psrc = (float*)d_ws;
    float* pdst = psrc + 4 * (size_t)NN;
    float* psum = pdst + 4 * (size_t)NN;
    float* part = psum + (size_t)CC * NN;
    u16*   Wt   = (u16*)(part + (size_t)CC * NN * FOUT);
    u16*   whT  = Wt + (size_t)FOUT * FIN;

    k_wt  <<<dim3(FOUT / 64, FIN / 64), 256, 0, stream>>>(W, Wt);
    k_proj<<<dim3(FOUT / 64, NN / 32), 256, 0, stream>>>(h, Wt, b, a1, a2, whT, psrc, pdst);
    k_attn<<<dim3(NN / BI, CC), 256, 0, stream>>>(adj, whT, psrc, pdst, ab, part, psum);
    k_fin <<<(NN * FOUT / 4) / 256, 256, 0, stream>>>(part, psum, out);
}

// Round 8
// 178.601 us; speedup vs baseline: 1.0307x; 1.0307x over previous
//
#include <hip/hip_runtime.h>

#define NN   4096
#define FIN  512
#define FOUT 256
#define ALPHA 0.2f

typedef __attribute__((ext_vector_type(8))) short short8;
typedef __attribute__((ext_vector_type(4))) float f32x4;
typedef unsigned short u16;

__device__ __forceinline__ u16 f2bf(float x) {   // round-to-nearest-even
    union { float f; unsigned u; } v; v.f = x;
    unsigned r = v.u + 0x7FFF + ((v.u >> 16) & 1);
    return (u16)(r >> 16);
}

// ---------------- Kernel 0: Wt[f][k] bf16 = transpose(W [k][f] fp32) ----------------
__global__ __launch_bounds__(256) void k_wt(const float* __restrict__ W,
                                            u16* __restrict__ Wt) {
    __shared__ float s[64 * 65];
    const int t  = threadIdx.x;
    const int f0 = blockIdx.x * 64;
    const int k0 = blockIdx.y * 64;
    #pragma unroll
    for (int p = 0; p < 4; ++p) {
        int q = t + 256 * p, rr = q >> 4, cc = q & 15;
        float4 w4 = *(const float4*)&W[(size_t)(k0 + rr) * FOUT + f0 + cc * 4];
        s[(cc * 4 + 0) * 65 + rr] = w4.x;
        s[(cc * 4 + 1) * 65 + rr] = w4.y;
        s[(cc * 4 + 2) * 65 + rr] = w4.z;
        s[(cc * 4 + 3) * 65 + rr] = w4.w;
    }
    __syncthreads();
    #pragma unroll
    for (int p = 0; p < 4; ++p) {
        int q = t + 256 * p, f = q >> 4, kg = q & 15;
        ushort4 o;
        o.x = f2bf(s[f * 65 + kg * 4 + 0]);
        o.y = f2bf(s[f * 65 + kg * 4 + 1]);
        o.z = f2bf(s[f * 65 + kg * 4 + 2]);
        o.w = f2bf(s[f * 65 + kg * 4 + 3]);
        *(ushort4*)&Wt[(size_t)(f0 + f) * FIN + k0 + kg * 4] = o;
    }
}

// ------- Kernel 1: whT bf16 tiles + partial f_src/f_dst (k_vec folded in) -------
#define HS 520   // u16 LDS row stride
__global__ __launch_bounds__(256) void k_proj(const float* __restrict__ h,
                                              const u16* __restrict__ Wt,
                                              const float* __restrict__ bias,
                                              const float* __restrict__ a1,
                                              const float* __restrict__ a2,
                                              u16* __restrict__ whT,
                                              float* __restrict__ psrc,
                                              float* __restrict__ pdst) {
    __shared__ u16   s_h[32 * HS];     // 32 x 512 bf16
    __shared__ float s_red[4 * 32];
    const int t  = threadIdx.x;
    const int f0 = blockIdx.x * 64;
    const int i0 = blockIdx.y * 32;
    #pragma unroll
    for (int p = 0; p < 16; ++p) {
        int q = t + 256 * p, row = q >> 7, c4 = q & 127;
        float4 v = *(const float4*)&h[(size_t)(i0 + row) * FIN + c4 * 4];
        ushort4 o; o.x = f2bf(v.x); o.y = f2bf(v.y); o.z = f2bf(v.z); o.w = f2bf(v.w);
        *(ushort4*)&s_h[row * HS + c4 * 4] = o;
    }
    __syncthreads();
    const int w = t >> 6, l = t & 63, n = l & 15, quad = l >> 4;
    const int hh = w & 1, fh = w >> 1;
    f32x4 acc[2] = {{0.f,0.f,0.f,0.f},{0.f,0.f,0.f,0.f}};
    #pragma unroll
    for (int k0 = 0; k0 < FIN; k0 += 32) {
        short8 a  = *(const short8*)&s_h[(hh * 16 + n) * HS + k0 + quad * 8];
        short8 b0 = *(const short8*)&Wt[(size_t)(f0 + fh * 32 + n) * FIN + k0 + quad * 8];
        short8 b1 = *(const short8*)&Wt[(size_t)(f0 + fh * 32 + 16 + n) * FIN + k0 + quad * 8];
        acc[0] = __builtin_amdgcn_mfma_f32_16x16x32_bf16(a, b0, acc[0], 0, 0, 0);
        acc[1] = __builtin_amdgcn_mfma_f32_16x16x32_bf16(a, b1, acc[1], 0, 0, 0);
    }
    u16* wt_tile = whT + (size_t)(i0 >> 5) * (FOUT * 32);
    float a1v[2], a2v[2];
    a1v[0] = a1[f0 + fh * 32 + n];      a1v[1] = a1[f0 + fh * 32 + 16 + n];
    a2v[0] = a2[f0 + fh * 32 + n];      a2v[1] = a2[f0 + fh * 32 + 16 + n];
    float ps[4] = {0.f,0.f,0.f,0.f}, pd[4] = {0.f,0.f,0.f,0.f};
    #pragma unroll
    for (int u = 0; u < 2; ++u) {
        const int f = f0 + fh * 32 + u * 16 + n;
        const float bv = bias[f];
        #pragma unroll
        for (int r = 0; r < 4; ++r) {
            float val = acc[u][r] + bv;                      // D: row=quad*4+r, col=n
            wt_tile[f * 32 + hh * 16 + quad * 4 + r] = f2bf(val);
            ps[r] += val * a1v[u];
            pd[r] += val * a2v[u];
        }
    }
    #pragma unroll
    for (int m = 1; m < 16; m <<= 1) {
        #pragma unroll
        for (int r = 0; r < 4; ++r) { ps[r] += __shfl_xor(ps[r], m); pd[r] += __shfl_xor(pd[r], m); }
    }
    if (n == 0) {
        #pragma unroll
        for (int r = 0; r < 4; ++r) {
            int il = hh * 16 + quad * 4 + r;
            s_red[fh * 32 + il]       = ps[r];
            s_red[64 + fh * 32 + il]  = pd[r];
        }
    }
    __syncthreads();
    if (t < 32) {
        psrc[(size_t)blockIdx.x * NN + i0 + t] = s_red[t]      + s_red[32 + t];
        pdst[(size_t)blockIdx.x * NN + i0 + t] = s_red[64 + t] + s_red[96 + t];
    }
}

// ------ Kernel 2: zero-redundancy, zero-barrier-loop fused attn ------
// One wave owns 16 i-rows x ALL 256 f. Softmax row-factor exp(fs_i) cancels:
//   q_ij = adj ? (fd_j > -fs_i ? F_j : R_i*H_j) : 0
//   F=exp(fd), H=exp(0.2 fd) (LDS, per chunk), R_i=exp(-0.8 fs_i) (per lane).
// No transcendentals in the K-loop; A-frag built lane-locally from adj regs.
#define CC 8
#define JCHUNK (NN / CC)          // 512
#define TJ 32
#define NITER  (JCHUNK / TJ)      // 16
__global__ __launch_bounds__(256, 2) void k_attn(const int* __restrict__ adj,
                                                 const u16* __restrict__ whT,
                                                 const float* __restrict__ psrc,
                                                 const float* __restrict__ pdst,
                                                 const float* __restrict__ ab,
                                                 float* __restrict__ part,
                                                 float* __restrict__ psum) {
    __shared__ float s_F[JCHUNK];      // exp(fd_j)
    __shared__ float s_H[JCHUNK];      // exp(0.2*fd_j)
    const int t  = threadIdx.x;
    const int c  = blockIdx.y;
    const int jbeg = c * JCHUNK;
    const int w = t >> 6, l = t & 63, n = l & 15, quad = l >> 4;
    const int i0w = blockIdx.x * 64 + w * 16;    // this wave's 16 rows

    // ---- preamble: fd -> F,H into LDS (block-wide, once) ----
    if (t < JCHUNK / 4) {
        float4 v0 = ((const float4*)&pdst[jbeg])[t];
        float4 v1 = ((const float4*)&pdst[NN + jbeg])[t];
        float4 v2 = ((const float4*)&pdst[2 * NN + jbeg])[t];
        float4 v3 = ((const float4*)&pdst[3 * NN + jbeg])[t];
        float4 fd4;
        fd4.x = v0.x + v1.x + v2.x + v3.x; fd4.y = v0.y + v1.y + v2.y + v3.y;
        fd4.z = v0.z + v1.z + v2.z + v3.z; fd4.w = v0.w + v1.w + v2.w + v3.w;
        float4 F4, H4;
        F4.x = __expf(fd4.x); F4.y = __expf(fd4.y); F4.z = __expf(fd4.z); F4.w = __expf(fd4.w);
        H4.x = __expf(0.2f * fd4.x); H4.y = __expf(0.2f * fd4.y);
        H4.z = __expf(0.2f * fd4.z); H4.w = __expf(0.2f * fd4.w);
        ((float4*)s_F)[t] = F4;
        ((float4*)s_H)[t] = H4;
    }
    const float fsm = psrc[i0w + n] + psrc[NN + i0w + n] + psrc[2 * NN + i0w + n]
                    + psrc[3 * NN + i0w + n] + ab[0];
    const float Ein = __expf(-fsm);          // pos branch iff F_j > Ein
    const float Rn  = __expf(-0.8f * fsm);
    __syncthreads();                         // only barrier in the kernel

    const int* arow = adj + (size_t)(i0w + n) * NN + jbeg + quad * 8;
    int4 a0 = *(const int4*)arow;            // jj 0..3
    int4 a1 = *(const int4*)(arow + 4);      // jj 4..7

    f32x4 acc[16];
    #pragma unroll
    for (int u = 0; u < 16; ++u) acc[u] = (f32x4){0.f, 0.f, 0.f, 0.f};
    float rs = 0.f;

    for (int it = 0; it < NITER; ++it) {
        const int jo = it * TJ;
        float4 F0 = *(const float4*)&s_F[jo + quad * 8];
        float4 F1 = *(const float4*)&s_F[jo + quad * 8 + 4];
        float4 H0 = *(const float4*)&s_H[jo + quad * 8];
        float4 H1 = *(const float4*)&s_H[jo + quad * 8 + 4];
        short8 af;
        {
            float qq;
#define MK(e, Fc, Hc, Ac) \
            qq = (Fc > Ein) ? Fc : Rn * Hc; \
            qq = (Ac > 0) ? qq : 0.f; \
            af[e] = (short)f2bf(qq); rs += qq;
            MK(0, F0.x, H0.x, a0.x)  MK(1, F0.y, H0.y, a0.y)
            MK(2, F0.z, H0.z, a0.z)  MK(3, F0.w, H0.w, a0.w)
            MK(4, F1.x, H1.x, a1.x)  MK(5, F1.y, H1.y, a1.y)
            MK(6, F1.z, H1.z, a1.z)  MK(7, F1.w, H1.w, a1.w)
#undef MK
        }
        // prefetch next iter's adj (in flight through the MFMA phase)
        if (it + 1 < NITER) {
            a0 = *(const int4*)(arow + TJ);
            a1 = *(const int4*)(arow + TJ + 4);
            arow += TJ;
        }
        // 16 B-frags (all 256 f) from L2/L1-hot whT, 16 MFMAs
        const u16* tb = whT + (size_t)((jbeg + jo) >> 5) * (FOUT * 32) + quad * 8;
        #pragma unroll
        for (int u = 0; u < 16; ++u) {
            short8 b = *(const short8*)&tb[(u * 16 + n) * 32];
            acc[u] = __builtin_amdgcn_mfma_f32_16x16x32_bf16(af, b, acc[u], 0, 0, 0);
        }
    }
    // ---- row denominators: sum quads; lane m=n holds row i0w+n ----
    rs += __shfl_xor(rs, 16);
    rs += __shfl_xor(rs, 32);
    if (l < 16) psum[(size_t)c * NN + i0w + l] = rs;
    // ---- partial numerators: D row = quad*4+r, col = n ----
    float* pc = part + ((size_t)c * NN + i0w) * FOUT;
    #pragma unroll
    for (int u = 0; u < 16; ++u)
        #pragma unroll
        for (int r = 0; r < 4; ++r)
            pc[(size_t)(quad * 4 + r) * FOUT + u * 16 + n] = acc[u][r];
}

// ------ Kernel 3: combine partials, normalize, elu ------
__global__ __launch_bounds__(256) void k_fin(const float* __restrict__ part,
                                             const float* __restrict__ psum,
                                             float* __restrict__ out) {
    const int g = blockIdx.x * 256 + threadIdx.x;
    const int i = g >> 6;
    const size_t s4 = (size_t)NN * (FOUT / 4);
    float4 a = ((const float4*)part)[g];
    float s = psum[i];
    #pragma unroll
    for (int c = 1; c < CC; ++c) {
        float4 bb = ((const float4*)part)[g + (size_t)c * s4];
        a.x += bb.x; a.y += bb.y; a.z += bb.z; a.w += bb.w;
        s += psum[(size_t)c * NN + i];
    }
    const float inv = 1.0f / s;
    a.x *= inv; a.y *= inv; a.z *= inv; a.w *= inv;
    a.x = a.x > 0.f ? a.x : __expf(a.x) - 1.f;
    a.y = a.y > 0.f ? a.y : __expf(a.y) - 1.f;
    a.z = a.z > 0.f ? a.z : __expf(a.z) - 1.f;
    a.w = a.w > 0.f ? a.w : __expf(a.w) - 1.f;
    ((float4*)out)[g] = a;
}

extern "C" void kernel_launch(void* const* d_in, const int* in_sizes, int n_in,
                              void* d_out, int out_size, void* d_ws, size_t ws_size,
                              hipStream_t stream) {
    const int*   adj = (const int*)  d_in[0];
    const float* h   = (const float*)d_in[1];
    const float* W   = (const float*)d_in[2];
    const float* b   = (const float*)d_in[3];
    const float* a1  = (const float*)d_in[4];
    const float* a2  = (const float*)d_in[5];
    const float* ab  = (const float*)d_in[6];
    float* out = (float*)d_out;

    // layout: psrc[4][NN] | pdst[4][NN] | psum[CC][NN] | part[CC][NN][FOUT] |
    // Wt (u16) | whT (u16)   (~36 MB total; ws observed ~268 MB)
    float* psrc = (float*)d_ws;
    float* pdst = psrc + 4 * (size_t)NN;
    float* psum = pdst + 4 * (size_t)NN;
    float* part = psum + (size_t)CC * NN;
    u16*   Wt   = (u16*)(part + (size_t)CC * NN * FOUT);
    u16*   whT  = Wt + (size_t)FOUT * FIN;

    k_wt  <<<dim3(FOUT / 64, FIN / 64), 256, 0, stream>>>(W, Wt);
    k_proj<<<dim3(FOUT / 64, NN / 32), 256, 0, stream>>>(h, Wt, b, a1, a2, whT, psrc, pdst);
    k_attn<<<dim3(NN / 64, CC), 256, 0, stream>>>(adj, whT, psrc, pdst, ab, part, psum);
    k_fin <<<(NN * FOUT / 4) / 256, 256, 0, stream>>>(part, psum, out);
}